// Round 1
// baseline (274.093 us; speedup 1.0000x reference)
//
#include <hip/hip_runtime.h>
#include <cstddef>

// Problem constants for this instance (setup_inputs is fixed):
//   feats: (B=4, C=256, H=160, W=160) float32
//   rois:  (N=512, 5) float32  [batch, x1, y1, x2, y2] (normalized, scale=160)
//   out:   (N, C, OH=14, OW=14) float32
#define RA_C  256
#define RA_H  160
#define RA_W  160
#define RA_OH 14
#define RA_OW 14
#define RA_SCALE 160.0f
#define RA_K  4   // channels per thread (weights amortized over K planes)

__global__ __launch_bounds__(256) void roi_align_kernel(
    const float* __restrict__ feats,
    const float* __restrict__ rois,
    float* __restrict__ out,
    int N)
{
    constexpr int S  = RA_OH * RA_OW;   // 196 spatial positions
    constexpr int CG = RA_C / RA_K;     // channel groups per roi
    constexpr int HW = RA_H * RA_W;

    int idx = blockIdx.x * blockDim.x + threadIdx.x;
    int total = N * CG * S;
    if (idx >= total) return;

    int s  = idx % S;
    int t  = idx / S;
    int cg = t % CG;
    int n  = t / CG;
    int oy = s / RA_OW;
    int ox = s - oy * RA_OW;

    // ---- per-(roi, spatial) interpolation parameters (shared by all channels)
    const float* r = rois + (size_t)n * 5;
    int   b  = (int)r[0];
    float x1 = r[1] * RA_SCALE;
    float y1 = r[2] * RA_SCALE;
    float rw = r[3] * RA_SCALE - x1;
    float rh = r[4] * RA_SCALE - y1;

    float gx = (float)ox * (1.0f / (RA_OW - 1));
    float gy = (float)oy * (1.0f / (RA_OH - 1));
    float fx = x1 + gx * rw;
    float fy = y1 + gy * rh;

    // ALIGNED == False transform (match reference arithmetic exactly)
    float nfx = fx / (float)RA_W * 2.0f - 1.0f;
    float nfy = fy / (float)RA_H * 2.0f - 1.0f;
    float ix  = ((nfx + 1.0f) * (float)RA_W - 1.0f) * 0.5f;
    float iy  = ((nfy + 1.0f) * (float)RA_H - 1.0f) * 0.5f;

    float x0f = floorf(ix), y0f = floorf(iy);
    int   x0  = (int)x0f,   y0  = (int)y0f;
    float wx1 = ix - x0f,   wx0 = 1.0f - wx1;
    float wy1 = iy - y0f,   wy0 = 1.0f - wy1;

    int xp = x0 + 1, yp = y0 + 1;
    bool vx0 = (x0 >= 0) && (x0 < RA_W);
    bool vx1 = (xp >= 0) && (xp < RA_W);
    bool vy0 = (y0 >= 0) && (y0 < RA_H);
    bool vy1 = (yp >= 0) && (yp < RA_H);

    int x0c = min(max(x0, 0), RA_W - 1);
    int x1c = min(max(xp, 0), RA_W - 1);
    int y0c = min(max(y0, 0), RA_H - 1);
    int y1c = min(max(yp, 0), RA_H - 1);

    float w00 = wy0 * wx0 * ((vy0 && vx0) ? 1.0f : 0.0f);
    float w01 = wy0 * wx1 * ((vy0 && vx1) ? 1.0f : 0.0f);
    float w10 = wy1 * wx0 * ((vy1 && vx0) ? 1.0f : 0.0f);
    float w11 = wy1 * wx1 * ((vy1 && vx1) ? 1.0f : 0.0f);

    int o00 = y0c * RA_W + x0c;
    int o01 = y0c * RA_W + x1c;
    int o10 = y1c * RA_W + x0c;
    int o11 = y1c * RA_W + x1c;

    int c0 = cg * RA_K;
    const float* fb = feats + ((size_t)b * RA_C + c0) * HW;
    float*       op = out   + ((size_t)n * RA_C + c0) * S + s;

#pragma unroll
    for (int k = 0; k < RA_K; ++k) {
        const float* f = fb + (size_t)k * HW;
        float v = f[o00] * w00 + f[o01] * w01 + f[o10] * w10 + f[o11] * w11;
        op[(size_t)k * S] = v;
    }
}

extern "C" void kernel_launch(void* const* d_in, const int* in_sizes, int n_in,
                              void* d_out, int out_size, void* d_ws, size_t ws_size,
                              hipStream_t stream) {
    const float* feats = (const float*)d_in[0];
    const float* rois  = (const float*)d_in[1];
    float*       out   = (float*)d_out;

    int N = in_sizes[1] / 5;               // 512 rois
    constexpr int S  = RA_OH * RA_OW;      // 196
    constexpr int CG = RA_C / RA_K;        // 64

    int total = N * CG * S;
    int block = 256;
    int grid  = (total + block - 1) / block;
    roi_align_kernel<<<grid, block, 0, stream>>>(feats, rois, out, N);
}

// Round 2
// 241.443 us; speedup vs baseline: 1.1352x; 1.1352x over previous
//
#include <hip/hip_runtime.h>
#include <cstddef>

// Problem constants (setup_inputs is fixed):
//   feats: (B=4, C=256, H=160, W=160) float32  = 105 MB
//   rois:  (N=512, 5) float32  [batch, x1, y1, x2, y2] (normalized, scale=160)
//   out:   (N, C, OH=14, OW=14) float32        = 103 MB
//
// R2 schedule: channel-group (cg) is the SLOW axis and is sliced across XCDs
// (xcd = blockIdx % 8 owns cg in [xcd*CG/8, ...)). Cross-RoI reuse of feat
// lines (128 rois/image, overlapping) is then captured in the 4 MB per-XCD L2:
// per-XCD working set ~= 1-2 cg x 4ch x 4img x 102 KB ~= 1.6-3.2 MB. Each
// channel is fetched by exactly one XCD -> HBM fetch ~ compulsory 105 MB
// (R1 measured 359 MB with n-slowest order).
#define RA_C  256
#define RA_H  160
#define RA_W  160
#define RA_OH 14
#define RA_OW 14
#define RA_SCALE 160.0f
#define RA_K  4   // channels per thread (weights amortized over K planes)
#define RA_NXCD 8

__global__ __launch_bounds__(256) void roi_align_kernel(
    const float* __restrict__ feats,
    const float* __restrict__ rois,
    float* __restrict__ out,
    int N,
    int bpc)   // blocks per channel-group = ceil(N*S/256)
{
    constexpr int S   = RA_OH * RA_OW;   // 196 spatial positions
    constexpr int CG  = RA_C / RA_K;     // 64 channel groups
    constexpr int CGX = CG / RA_NXCD;    // 8 cgs per XCD slice
    constexpr int HW  = RA_H * RA_W;

    // ---- XCD-aware decomposition: bid = (local * 8) + xcd (HW round-robin)
    int bid   = blockIdx.x;
    int xcd   = bid & (RA_NXCD - 1);
    int local = bid >> 3;                // 0 .. CGX*bpc-1
    int cg    = xcd * CGX + local / bpc; // this XCD's channel slice
    int rem   = local - (local / bpc) * bpc;

    int idx_in_cg = rem * 256 + (int)threadIdx.x;   // over (n, s)
    if (idx_in_cg >= N * S) return;

    int n = idx_in_cg / S;
    int s = idx_in_cg - n * S;
    int oy = s / RA_OW;
    int ox = s - oy * RA_OW;

    // ---- per-(roi, spatial) interpolation parameters (shared by all channels)
    const float* r = rois + (size_t)n * 5;
    int   b  = (int)r[0];
    float x1 = r[1] * RA_SCALE;
    float y1 = r[2] * RA_SCALE;
    float rw = r[3] * RA_SCALE - x1;
    float rh = r[4] * RA_SCALE - y1;

    float gx = (float)ox * (1.0f / (RA_OW - 1));
    float gy = (float)oy * (1.0f / (RA_OH - 1));
    float fx = x1 + gx * rw;
    float fy = y1 + gy * rh;

    // ALIGNED == False transform (match reference arithmetic exactly)
    float nfx = fx / (float)RA_W * 2.0f - 1.0f;
    float nfy = fy / (float)RA_H * 2.0f - 1.0f;
    float ix  = ((nfx + 1.0f) * (float)RA_W - 1.0f) * 0.5f;
    float iy  = ((nfy + 1.0f) * (float)RA_H - 1.0f) * 0.5f;

    float x0f = floorf(ix), y0f = floorf(iy);
    int   x0  = (int)x0f,   y0  = (int)y0f;
    float wx1 = ix - x0f,   wx0 = 1.0f - wx1;
    float wy1 = iy - y0f,   wy0 = 1.0f - wy1;

    int xp = x0 + 1, yp = y0 + 1;
    bool vx0 = (x0 >= 0) && (x0 < RA_W);
    bool vx1 = (xp >= 0) && (xp < RA_W);
    bool vy0 = (y0 >= 0) && (y0 < RA_H);
    bool vy1 = (yp >= 0) && (yp < RA_H);

    int x0c = min(max(x0, 0), RA_W - 1);
    int x1c = min(max(xp, 0), RA_W - 1);
    int y0c = min(max(y0, 0), RA_H - 1);
    int y1c = min(max(yp, 0), RA_H - 1);

    float w00 = wy0 * wx0 * ((vy0 && vx0) ? 1.0f : 0.0f);
    float w01 = wy0 * wx1 * ((vy0 && vx1) ? 1.0f : 0.0f);
    float w10 = wy1 * wx0 * ((vy1 && vx0) ? 1.0f : 0.0f);
    float w11 = wy1 * wx1 * ((vy1 && vx1) ? 1.0f : 0.0f);

    int o00 = y0c * RA_W + x0c;
    int o01 = y0c * RA_W + x1c;
    int o10 = y1c * RA_W + x0c;
    int o11 = y1c * RA_W + x1c;

    int c0 = cg * RA_K;
    const float* fb = feats + ((size_t)b * RA_C + c0) * HW;
    float*       op = out   + ((size_t)n * RA_C + c0) * S + s;

#pragma unroll
    for (int k = 0; k < RA_K; ++k) {
        const float* f = fb + (size_t)k * HW;
        float v = f[o00] * w00 + f[o01] * w01 + f[o10] * w10 + f[o11] * w11;
        op[(size_t)k * S] = v;
    }
}

extern "C" void kernel_launch(void* const* d_in, const int* in_sizes, int n_in,
                              void* d_out, int out_size, void* d_ws, size_t ws_size,
                              hipStream_t stream) {
    const float* feats = (const float*)d_in[0];
    const float* rois  = (const float*)d_in[1];
    float*       out   = (float*)d_out;

    int N = in_sizes[1] / 5;               // 512 rois
    constexpr int S  = RA_OH * RA_OW;      // 196
    constexpr int CG = RA_C / RA_K;        // 64

    int bpc  = (N * S + 255) / 256;        // blocks per channel group (392)
    int grid = CG * bpc;                   // 25088 blocks, divisible by 8
    roi_align_kernel<<<grid, 256, 0, stream>>>(feats, rois, out, N, bpc);
}

// Round 3
// 232.502 us; speedup vs baseline: 1.1789x; 1.0385x over previous
//
#include <hip/hip_runtime.h>
#include <cstddef>
#include <cstring>

// Problem constants (setup_inputs is fixed):
//   feats: (B=4, C=256, H=160, W=160) float32  = 105 MB
//   rois:  (N=512, 5) float32  [batch, x1, y1, x2, y2] (normalized, scale=160)
//   out:   (N, C, OH=14, OW=14) float32        = 103 MB
//
// R2: channel-group slow axis + XCD slicing -> fetch 359->46 MB (L2/L3 capture
//     cross-RoI reuse). Left: gather wave-instr throughput (1.6M gather instrs
//     x ~40 cyc of TA splitting).
// R3: (a) x-corner pair loaded as one float2 (adjacent floats) with clamp+swap
//     trick -> gather instrs halved; (b) K=4->8 channels/thread to amortize
//     address math (thread count halved, same load count, more ILP).
#define RA_C  256
#define RA_H  160
#define RA_W  160
#define RA_OH 14
#define RA_OW 14
#define RA_SCALE 160.0f
#define RA_K  8    // channels per thread
#define RA_NXCD 8

__device__ __forceinline__ float2 ldg_f2(const float* p) {
    float2 r;
    __builtin_memcpy(&r, p, sizeof(float2));   // 4B-aligned; gfx950 supports
    return r;                                  // unaligned dwordx2
}

__global__ __launch_bounds__(256) void roi_align_kernel(
    const float* __restrict__ feats,
    const float* __restrict__ rois,
    float* __restrict__ out,
    int N,
    int bpc)   // blocks per channel-group = ceil(N*S/256)
{
    constexpr int S   = RA_OH * RA_OW;   // 196 spatial positions
    constexpr int CG  = RA_C / RA_K;     // 32 channel groups
    constexpr int CGX = CG / RA_NXCD;    // 4 cgs per XCD slice
    constexpr int HW  = RA_H * RA_W;

    // ---- XCD-aware decomposition: bid = (local * 8) + xcd (HW round-robin)
    int bid   = blockIdx.x;
    int xcd   = bid & (RA_NXCD - 1);
    int local = bid >> 3;
    int cg    = xcd * CGX + local / bpc;
    int rem   = local - (local / bpc) * bpc;

    int idx_in_cg = rem * 256 + (int)threadIdx.x;   // over (n, s), s fast
    if (idx_in_cg >= N * S) return;

    int n = idx_in_cg / S;
    int s = idx_in_cg - n * S;
    int oy = s / RA_OW;
    int ox = s - oy * RA_OW;

    // ---- per-(roi, spatial) interpolation parameters (shared by all channels)
    const float* r = rois + (size_t)n * 5;
    int   b  = (int)r[0];
    float x1 = r[1] * RA_SCALE;
    float y1 = r[2] * RA_SCALE;
    float rw = r[3] * RA_SCALE - x1;
    float rh = r[4] * RA_SCALE - y1;

    float gx = (float)ox * (1.0f / (RA_OW - 1));
    float gy = (float)oy * (1.0f / (RA_OH - 1));
    float fx = x1 + gx * rw;
    float fy = y1 + gy * rh;

    // ALIGNED == False transform (match reference arithmetic exactly)
    float nfx = fx / (float)RA_W * 2.0f - 1.0f;
    float nfy = fy / (float)RA_H * 2.0f - 1.0f;
    float ix  = ((nfx + 1.0f) * (float)RA_W - 1.0f) * 0.5f;
    float iy  = ((nfy + 1.0f) * (float)RA_H - 1.0f) * 0.5f;

    float x0f = floorf(ix), y0f = floorf(iy);
    int   x0  = (int)x0f,   y0  = (int)y0f;
    float wx1 = ix - x0f,   wx0 = 1.0f - wx1;
    float wy1 = iy - y0f,   wy0 = 1.0f - wy1;

    int xp = x0 + 1, yp = y0 + 1;
    bool vx0 = (x0 >= 0) && (x0 < RA_W);
    bool vx1 = (xp >= 0) && (xp < RA_W);
    bool vy0 = (y0 >= 0) && (y0 < RA_H);
    bool vy1 = (yp >= 0) && (yp < RA_H);

    float w00 = wy0 * wx0 * ((vy0 && vx0) ? 1.0f : 0.0f);
    float w01 = wy0 * wx1 * ((vy0 && vx1) ? 1.0f : 0.0f);
    float w10 = wy1 * wx0 * ((vy1 && vx0) ? 1.0f : 0.0f);
    float w11 = wy1 * wx1 * ((vy1 && vx1) ? 1.0f : 0.0f);

    // ---- x-pair window: load float2 at px, px in [0, W-2].
    // If clamping shifted the window (x0 != px), the valid corner sits in the
    // OTHER slot and the displaced slot's weight is 0 -> swap coefficients.
    int  px   = min(max(x0, 0), RA_W - 2);
    bool swp  = (x0 != px);
    float a0 = swp ? w01 : w00;   // coeff on pair.x, row y0
    float b0 = swp ? w00 : w01;   // coeff on pair.y, row y0
    float a1 = swp ? w11 : w10;   // row y1
    float b1 = swp ? w10 : w11;

    int y0c = min(max(y0, 0), RA_H - 1);
    int y1c = min(max(yp, 0), RA_H - 1);
    int o0  = y0c * RA_W + px;    // pair covers (px, px+1), always in-row
    int o1  = y1c * RA_W + px;

    int c0 = cg * RA_K;
    const float* fb = feats + ((size_t)b * RA_C + c0) * HW;
    float*       op = out   + ((size_t)n * RA_C + c0) * S + s;

#pragma unroll
    for (int k = 0; k < RA_K; ++k) {
        const float* f = fb + (size_t)k * HW;
        float2 p0 = ldg_f2(f + o0);
        float2 p1 = ldg_f2(f + o1);
        float v = fmaf(a0, p0.x, fmaf(b0, p0.y, fmaf(a1, p1.x, b1 * p1.y)));
        op[(size_t)k * S] = v;
    }
}

extern "C" void kernel_launch(void* const* d_in, const int* in_sizes, int n_in,
                              void* d_out, int out_size, void* d_ws, size_t ws_size,
                              hipStream_t stream) {
    const float* feats = (const float*)d_in[0];
    const float* rois  = (const float*)d_in[1];
    float*       out   = (float*)d_out;

    int N = in_sizes[1] / 5;               // 512 rois
    constexpr int S  = RA_OH * RA_OW;      // 196
    constexpr int CG = RA_C / RA_K;        // 32

    int bpc  = (N * S + 255) / 256;        // 392 blocks per channel group
    int grid = CG * bpc;                   // 12544 blocks, divisible by 8
    roi_align_kernel<<<grid, 256, 0, stream>>>(feats, rois, out, N, bpc);
}